// Round 14
// baseline (533.167 us; speedup 1.0000x reference)
//
#include <hip/hip_runtime.h>
#include <math.h>

#define NN     50000
#define FF     256
#define HH     64
#define NHEADS 4
#define EE     800000
#define OUTD   16

typedef __attribute__((ext_vector_type(8))) short short8;
typedef __attribute__((ext_vector_type(4))) float f32x4;

__device__ inline unsigned short f2bf(float f) {
    unsigned u = __builtin_bit_cast(unsigned, f);
    unsigned r = (u + 0x7fff + ((u >> 16) & 1)) >> 16;
    return (unsigned short)r;
}
__device__ inline float bf2f(unsigned short s) {
    unsigned u = ((unsigned)s) << 16;
    return __builtin_bit_cast(float, u);
}

// ---------------------------------------------------------------------------
// Weight packing helper (fragment layout; hi/lo bf16 split optional).
// ---------------------------------------------------------------------------
__device__ inline void pack_one(const float* __restrict__ W,
                                unsigned short* __restrict__ bhi,
                                unsigned short* __restrict__ blo,
                                int t_, int NT, int NTOT, int TOFF, int SRC_NC) {
    int lane = t_ & 63;
    int tile = (t_ >> 6) % NT;
    int kb = (t_ >> 6) / NT;
    int q = lane >> 4, c = lane & 15;
    size_t off = ((size_t)(kb * NTOT + TOFF + tile) * 64 + lane) * 8;
#pragma unroll
    for (int j = 0; j < 8; j++) {
        float w = W[(size_t)(kb * 32 + q * 8 + j) * SRC_NC + tile * 16 + c];
        unsigned short h = f2bf(w);
        bhi[off + j] = h;
        if (blo) blo[off + j] = f2bf(w - bf2f(h));
    }
}

#define NTT 20
#define CSRB 512

// ---------------------------------------------------------------------------
// ONE-KERNEL CSR build + weight pack (round-14: 6 graph nodes -> 1; ~10 us
// gap per node was ~100 us total across 11 nodes). Phases separated by
// device-scope atomic flag barriers. Safety: ALL intra-kernel cross-block
// data moves through device-scope atomics (cnt, partial, cursor); rowstart/
// dinv/col/packed-W are consumed only by later kernels (boundary-visible).
// All 512 blocks publish their flag BEFORE polling -> deadlock-free, and
// 512 << co-residency capacity (~2048 at this kernel's occupancy).
// flags[0..15] + partial[0..255] must be memset to 0 before launch.
// ---------------------------------------------------------------------------
__global__ __launch_bounds__(256) void k_csr_build(
        const int* __restrict__ esrc, const int* __restrict__ edst,
        const float* __restrict__ Wg1, const float* __restrict__ Wgat1,
        const float* __restrict__ Wg2, const float* __restrict__ Wgat2,
        unsigned short* __restrict__ bhiC,
        unsigned short* __restrict__ bhiG2, unsigned short* __restrict__ bloG2,
        unsigned short* __restrict__ bhiA2, unsigned short* __restrict__ bloA2,
        int* __restrict__ cnt, int* __restrict__ rowstart,
        int* __restrict__ cursor, float* __restrict__ dinv,
        int* __restrict__ col, int* __restrict__ flags, int* __restrict__ partial) {
    const int tid = threadIdx.x;
    const int bx = blockIdx.x;
    const int gid = bx * 256 + tid;
    const int gsz = CSRB * 256;
    const int NCH = (NN + 255) / 256;   // 196 scan chunks

    // ---- P0: zero cnt (atomically — count's RMW must see it) + pack W ----
    for (int i = gid; i < NN; i += gsz) atomicExch(&cnt[i], 0);
    if (gid < 2048)                       pack_one(Wg1,   bhiC,  nullptr, gid,          4,  NTT, 0, 64);
    else if (gid < 10240)                 pack_one(Wgat1, bhiC,  nullptr, gid - 2048,   16, NTT, 4, 256);
    else if (gid < 10368)                 pack_one(Wg2,   bhiG2, bloG2,   gid - 10240,  1,  1,   0, 16);
    else if (gid < 10880)                 pack_one(Wgat2, bhiA2, bloA2,   gid - 10368,  1,  1,   0, 16);
    __syncthreads();
    if (tid == 0) {
        __threadfence();
        atomicAdd(&flags[0], 1);
        while (atomicAdd(&flags[0], 0) < CSRB) __builtin_amdgcn_s_sleep(2);
    }
    __syncthreads();
    __threadfence();

    // ---- P1: count in-degrees ----
    for (int e = gid; e < EE; e += gsz) atomicAdd(&cnt[edst[e]], 1);
    __syncthreads();
    if (tid == 0) {
        __threadfence();
        atomicAdd(&flags[1], 1);
        while (atomicAdd(&flags[1], 0) < CSRB) __builtin_amdgcn_s_sleep(2);
    }
    __syncthreads();
    __threadfence();

    // ---- P2: scan (blocks 0..NCH-1) ----
    __shared__ int arr[256];
    __shared__ int poff[256];
    if (bx < NCH) {
        int i = bx * 256 + tid;
        int c = (i < NN) ? atomicAdd(&cnt[i], 0) : 0;   // atomic read: coherent
        arr[tid] = c;
        __syncthreads();
#pragma unroll
        for (int off = 1; off < 256; off <<= 1) {
            int v = arr[tid];
            int add = (tid >= off) ? arr[tid - off] : 0;
            __syncthreads();
            arr[tid] = v + add;
            __syncthreads();
        }
        int incl = arr[tid];
        int ctotal = arr[255];
        if (tid == 0) atomicExch(&partial[bx], ctotal + 1);   // +1 sentinel
        // poll all chunk totals (each published before any block polls others)
        int pv = 0;
        if (tid < NCH) {
            while ((pv = atomicAdd(&partial[tid], 0)) == 0) __builtin_amdgcn_s_sleep(2);
            pv -= 1;
        }
        poff[tid] = pv;
        __syncthreads();
#pragma unroll
        for (int off = 1; off < 256; off <<= 1) {
            int v = poff[tid];
            int add = (tid >= off) ? poff[tid - off] : 0;
            __syncthreads();
            poff[tid] = v + add;
            __syncthreads();
        }
        int blockoff = (bx > 0) ? poff[bx - 1] : 0;
        if (i < NN) {
            int excl = incl - c + blockoff;
            rowstart[i] = excl;                 // consumed by later kernels
            atomicExch(&cursor[i], excl);       // consumed by P3 atomics
            dinv[i] = rsqrtf((float)(c + 1));
        }
        if (bx == 0 && tid == 0) rowstart[NN] = EE;
        __syncthreads();
        if (tid == 0) {
            __threadfence();
            atomicAdd(&flags[2], 1);
        }
    }
    // ---- all blocks wait for scan, then fill ----
    if (tid == 0) {
        while (atomicAdd(&flags[2], 0) < NCH) __builtin_amdgcn_s_sleep(2);
    }
    __syncthreads();
    __threadfence();
    for (int e = gid; e < EE; e += gsz) {
        int d = edst[e];
        int pos = atomicAdd(&cursor[d], 1);
        col[pos] = esrc[e];                     // consumed by later kernels
    }
}

// ---------------------------------------------------------------------------
// FUSED big GEMM: one pass over x -> h1 (4 tiles, dinv-scaled) + hgat
// (16 tiles) + fused s1 scores. A split hi/lo (2 MFMAs/tile), B hi only.
// Barrier-free direct L2 reads of B (round-13). No async DMA (round-11).
// ---------------------------------------------------------------------------
__global__ __launch_bounds__(256) void mfma_gemm_fused(const float* __restrict__ A,
                                                       const unsigned short* __restrict__ Bhi,
                                                       unsigned short* __restrict__ Ch1,
                                                       unsigned short* __restrict__ Chg,
                                                       const float* __restrict__ dinv,
                                                       const float* __restrict__ a_s,
                                                       const float* __restrict__ a_d,
                                                       float* __restrict__ ssrc,
                                                       float* __restrict__ sdst,
                                                       int M) {
    const int K = 256;
    int tid = threadIdx.x;
    int w = tid >> 6, lane = tid & 63, q = lane >> 4, c = lane & 15;
    int row_base = blockIdx.x * 64 + w * 16;
    int ar = min(row_base + c, M - 1);
    const float* ap = A + (size_t)ar * K + q * 8;
    const short8* bp = (const short8*)Bhi + lane;

    f32x4 acc[NTT];
#pragma unroll
    for (int t = 0; t < NTT; t++) acc[t] = (f32x4){0.f, 0.f, 0.f, 0.f};

    for (int kb = 0; kb < 8; kb++) {
        float av[8];
        *(float4*)(av)     = *(const float4*)(ap + kb * 32);
        *(float4*)(av + 4) = *(const float4*)(ap + kb * 32 + 4);
        short8 ahi, alo;
#pragma unroll
        for (int j = 0; j < 8; j++) {
            unsigned short h = f2bf(av[j]);
            ahi[j] = (short)h;
            alo[j] = (short)f2bf(av[j] - bf2f(h));
        }
#pragma unroll
        for (int t = 0; t < NTT; t++) {
            short8 bhi = bp[(size_t)(kb * NTT + t) * 64];
            acc[t] = __builtin_amdgcn_mfma_f32_16x16x32_bf16(ahi, bhi, acc[t], 0, 0, 0);
            acc[t] = __builtin_amdgcn_mfma_f32_16x16x32_bf16(alo, bhi, acc[t], 0, 0, 0);
        }
    }

    // s1 scores over the 16 GAT tiles (tiles 4..19; head = (t-4)>>2)
#pragma unroll
    for (int i = 0; i < 4; i++) {
        int r = row_base + q * 4 + i;
        float ss[4] = {0.f, 0.f, 0.f, 0.f};
        float sd[4] = {0.f, 0.f, 0.f, 0.f};
#pragma unroll
        for (int t = 0; t < 16; t++) {
            float v = acc[t + 4][i];
            ss[t >> 2] += v * a_s[t * 16 + c];
            sd[t >> 2] += v * a_d[t * 16 + c];
        }
#pragma unroll
        for (int h = 0; h < 4; h++) {
#pragma unroll
            for (int off = 1; off <= 8; off <<= 1) {
                ss[h] += __shfl_xor(ss[h], off, 16);
                sd[h] += __shfl_xor(sd[h], off, 16);
            }
        }
        if (c == i && r < M) {
            *(float4*)(ssrc + (size_t)r * 4) = make_float4(ss[0], ss[1], ss[2], ss[3]);
            *(float4*)(sdst + (size_t)r * 4) = make_float4(sd[0], sd[1], sd[2], sd[3]);
        }
    }

#pragma unroll
    for (int i = 0; i < 4; i++) {
        int r = row_base + q * 4 + i;
        if (r < M) {
            float sc = dinv[r];
#pragma unroll
            for (int t = 0; t < 4; t++)
                Ch1[(size_t)r * 64 + t * 16 + c] = f2bf(acc[t][i] * sc);
#pragma unroll
            for (int t = 0; t < 16; t++)
                Chg[(size_t)r * 256 + t * 16 + c] = f2bf(acc[t + 4][i]);
        }
    }
}

// ---------------------------------------------------------------------------
// N=16 MFMA GEMM body; both small GEMMs in one launch (block-range split).
// ---------------------------------------------------------------------------
template <int KB, bool SCALE, bool SC2, int OFS>
__device__ inline void n16_body(int bx, int tid,
                                const unsigned short* __restrict__ A,
                                const unsigned short* __restrict__ Bhi,
                                const unsigned short* __restrict__ Blo,
                                unsigned short* __restrict__ Cbf,
                                const float* __restrict__ rowscale,
                                const float* __restrict__ a_s2,
                                const float* __restrict__ a_d2,
                                float* __restrict__ s2s,
                                float* __restrict__ s2d, int M) {
    const int K = KB * 32;
    int w = tid >> 6, lane = tid & 63, q = lane >> 4, c = lane & 15;
    int row_base = bx * 64 + w * 16;
    int ar = min(row_base + c, M - 1);
    const unsigned short* ap = A + (size_t)ar * K + q * 8;
    f32x4 acc = (f32x4){0.f, 0.f, 0.f, 0.f};
#pragma unroll
    for (int kb = 0; kb < KB; kb++) {
        short8 av = *(const short8*)(ap + kb * 32);
        size_t bo = ((size_t)kb * 64 + lane) * 8;
        short8 bh = *(const short8*)(Bhi + bo);
        short8 bl = *(const short8*)(Blo + bo);
        acc = __builtin_amdgcn_mfma_f32_16x16x32_bf16(av, bh, acc, 0, 0, 0);
        acc = __builtin_amdgcn_mfma_f32_16x16x32_bf16(av, bl, acc, 0, 0, 0);
    }
    if (SC2) {
#pragma unroll
        for (int i = 0; i < 4; i++) {
            float ps = acc[i] * a_s2[c];
            float pd = acc[i] * a_d2[c];
#pragma unroll
            for (int off = 1; off <= 8; off <<= 1) {
                ps += __shfl_xor(ps, off, 16);
                pd += __shfl_xor(pd, off, 16);
            }
            int r = row_base + q * 4 + i;
            if (c == i && r < M) {
                s2s[r] = ps;
                s2d[r] = pd;
            }
        }
    }
#pragma unroll
    for (int i = 0; i < 4; i++) {
        int r = row_base + q * 4 + i;
        if (r < M) {
            float sc = SCALE ? rowscale[r] : 1.0f;
            Cbf[((size_t)r * 16 + c) * 2 + OFS] = f2bf(acc[i] * sc);
        }
    }
}

__global__ __launch_bounds__(256) void mfma_n16_both(const unsigned short* __restrict__ Ag,
                                                     const unsigned short* __restrict__ Ac,
                                                     const unsigned short* __restrict__ bhiA2,
                                                     const unsigned short* __restrict__ bloA2,
                                                     const unsigned short* __restrict__ bhiG2,
                                                     const unsigned short* __restrict__ bloG2,
                                                     unsigned short* __restrict__ pairb,
                                                     const float* __restrict__ dinv,
                                                     const float* __restrict__ a_s2,
                                                     const float* __restrict__ a_d2,
                                                     float* __restrict__ s2s,
                                                     float* __restrict__ s2d,
                                                     int M, int GB) {
    int bx = blockIdx.x;
    if (bx < GB)
        n16_body<8, false, true, 1>(bx, threadIdx.x, Ag, bhiA2, bloA2, pairb,
                                    nullptr, a_s2, a_d2, s2s, s2d, M);
    else
        n16_body<2, true, false, 0>(bx - GB, threadIdx.x, Ac, bhiG2, bloG2, pairb,
                                    dinv, nullptr, nullptr, nullptr, nullptr, M);
}

// ---------------------------------------------------------------------------
// FUSED layer-1 aggregation: GAT1 (LDS-staged p/src, UNROLL-8 gather —
// round-14 MLP bump) + GCN1 riding the same sl[]. Fabric-floor bound.
// ---------------------------------------------------------------------------
__global__ __launch_bounds__(256) void both_agg(const unsigned short* __restrict__ hg,
                                                const unsigned short* __restrict__ h1,
                                                const int* __restrict__ rs,
                                                const int* __restrict__ col,
                                                const float* __restrict__ ssrc,
                                                const float* __restrict__ sdst,
                                                const float* __restrict__ dinv,
                                                const float* __restrict__ bgat,
                                                const float* __restrict__ bgcn,
                                                unsigned short* __restrict__ outg,
                                                unsigned short* __restrict__ outc) {
    __shared__ int s_lds[4][64];
    __shared__ float p_lds[4][64 * 4];
    int tid = threadIdx.x;
    int w = tid >> 6, lane = tid & 63;
    int wid = blockIdx.x * 4 + w;       // grid exact: 12500*4 = NN
    int hh = lane >> 4;
    int cidx = (lane & 15) * 4;
    int* sl = s_lds[w];
    float* pl = p_lds[w];

    float di = dinv[wid];
    float4 sd4 = *(const float4*)(sdst + (size_t)wid * 4);
    float sdv[4] = {sd4.x, sd4.y, sd4.z, sd4.w};
    float4 sf4 = *(const float4*)(ssrc + (size_t)wid * 4);
    float sfv[4] = {sf4.x, sf4.y, sf4.z, sf4.w};
    float psf[4];
#pragma unroll
    for (int h = 0; h < 4; h++) {
        float e = sfv[h] + sdv[h];
        e = (e >= 0.f) ? e : 0.2f * e;
        psf[h] = __expf(e);
    }
    float pse = (hh & 2) ? ((hh & 1) ? psf[3] : psf[2]) : ((hh & 1) ? psf[1] : psf[0]);
    const unsigned short* hbase = hg + lane * 4;
    ushort4 hvs = *(const ushort4*)(hbase + (size_t)wid * 256);
    float4 acc;
    acc.x = bf2f(hvs.x) * pse; acc.y = bf2f(hvs.y) * pse;
    acc.z = bf2f(hvs.z) * pse; acc.w = bf2f(hvs.w) * pse;
    float4 accc = make_float4(0.f, 0.f, 0.f, 0.f);

    float lsum[4] = {0.f, 0.f, 0.f, 0.f};
    int beg = rs[wid], end = rs[wid + 1];
    for (int j0 = beg; j0 < end; j0 += 64) {
        int cnt = min(64, end - j0);
        if (lane < cnt) {
            int sreg = col[j0 + lane];
            float4 sv = *(const float4*)(ssrc + (size_t)sreg * 4);
            float svv[4] = {sv.x, sv.y, sv.z, sv.w};
            float pv[4];
#pragma unroll
            for (int h = 0; h < 4; h++) {
                float e = svv[h] + sdv[h];
                e = (e >= 0.f) ? e : 0.2f * e;
                pv[h] = __expf(e);
                lsum[h] += pv[h];
            }
            sl[lane] = sreg;
            *(float4*)&pl[lane * 4] = make_float4(pv[0], pv[1], pv[2], pv[3]);
        }
        // same-wave LDS write->read: DS pipe in-order per wave, no barrier
        int e = 0;
        for (; e + 8 <= cnt; e += 8) {
            int sv0[8]; float pv0[8]; ushort4 hv[8];
#pragma unroll
            for (int u = 0; u < 8; u++) {
                sv0[u] = sl[e + u];
                pv0[u] = pl[(e + u) * 4 + hh];
            }
#pragma unroll
            for (int u = 0; u < 8; u++)
                hv[u] = *(const ushort4*)(hbase + (size_t)sv0[u] * 256);
#pragma unroll
            for (int u = 0; u < 8; u++) {
                acc.x += bf2f(hv[u].x) * pv0[u];
                acc.y += bf2f(hv[u].y) * pv0[u];
                acc.z += bf2f(hv[u].z) * pv0[u];
                acc.w += bf2f(hv[u].w) * pv0[u];
            }
        }
        for (; e < cnt; e++) {
            int s = sl[e];
            float p = pl[e * 4 + hh];
            ushort4 hv = *(const ushort4*)(hbase + (size_t)s * 256);
            acc.x += bf2f(hv.x) * p; acc.y += bf2f(hv.y) * p;
            acc.z += bf2f(hv.z) * p; acc.w += bf2f(hv.w) * p;
        }
        // GCN gather: group hh handles edges {hh, hh+4, ...}, 2 in flight
        int e2 = hh;
        for (; e2 + 4 < cnt; e2 += 8) {
            int sa = sl[e2], sb = sl[e2 + 4];
            ushort4 va = *(const ushort4*)(h1 + (size_t)sa * HH + cidx);
            ushort4 vb = *(const ushort4*)(h1 + (size_t)sb * HH + cidx);
            accc.x += bf2f(va.x) + bf2f(vb.x);
            accc.y += bf2f(va.y) + bf2f(vb.y);
            accc.z += bf2f(va.z) + bf2f(vb.z);
            accc.w += bf2f(va.w) + bf2f(vb.w);
        }
        if (e2 < cnt) {
            int sa = sl[e2];
            ushort4 va = *(const ushort4*)(h1 + (size_t)sa * HH + cidx);
            accc.x += bf2f(va.x); accc.y += bf2f(va.y);
            accc.z += bf2f(va.z); accc.w += bf2f(va.w);
        }
    }
    // GAT epilogue
#pragma unroll
    for (int h = 0; h < 4; h++) {
        float v = lsum[h];
        for (int off = 32; off >= 1; off >>= 1) v += __shfl_xor(v, off, 64);
        lsum[h] = v + psf[h];
    }
    float lt = (hh & 2) ? ((hh & 1) ? lsum[3] : lsum[2]) : ((hh & 1) ? lsum[1] : lsum[0]);
    float li = 1.0f / lt;
    float4 bv = *(const float4*)(bgat + lane * 4);
    ushort4 o;
    o.x = f2bf(fmaxf(acc.x * li + bv.x, 0.f));
    o.y = f2bf(fmaxf(acc.y * li + bv.y, 0.f));
    o.z = f2bf(fmaxf(acc.z * li + bv.z, 0.f));
    o.w = f2bf(fmaxf(acc.w * li + bv.w, 0.f));
    *(ushort4*)(outg + (size_t)wid * 256 + lane * 4) = o;
    // GCN epilogue
#pragma unroll
    for (int off = 16; off <= 32; off <<= 1) {
        accc.x += __shfl_xor(accc.x, off, 64);
        accc.y += __shfl_xor(accc.y, off, 64);
        accc.z += __shfl_xor(accc.z, off, 64);
        accc.w += __shfl_xor(accc.w, off, 64);
    }
    if (hh == 0) {
        ushort4 sv = *(const ushort4*)(h1 + (size_t)wid * HH + cidx);
        float4 bc = *(const float4*)(bgcn + cidx);
        ushort4 oc;
        oc.x = f2bf(fmaxf((accc.x + bf2f(sv.x)) * di + bc.x, 0.f));
        oc.y = f2bf(fmaxf((accc.y + bf2f(sv.y)) * di + bc.y, 0.f));
        oc.z = f2bf(fmaxf((accc.z + bf2f(sv.z)) * di + bc.z, 0.f));
        oc.w = f2bf(fmaxf((accc.w + bf2f(sv.w)) * di + bc.w, 0.f));
        *(ushort4*)(outc + (size_t)wid * HH + cidx) = oc;
    }
}

// ---------------------------------------------------------------------------
// Final aggregation: fused GCN2 + GAT2 over the interleaved pair buffer.
// ---------------------------------------------------------------------------
__global__ __launch_bounds__(256) void final_agg(const unsigned* __restrict__ hp,
                                                 const int* __restrict__ rs,
                                                 const int* __restrict__ col,
                                                 const float* __restrict__ dinv,
                                                 const float* __restrict__ s2s,
                                                 const float* __restrict__ s2d,
                                                 const float* __restrict__ bg2,
                                                 const float* __restrict__ bga2,
                                                 float* __restrict__ out) {
    int t = blockIdx.x * 256 + threadIdx.x;
    int node = t >> 4;
    int c = t & 15;
    float di = dinv[node];
    float sd = s2d[node];
    float es = s2s[node] + sd;
    es = (es >= 0.f) ? es : 0.2f * es;
    float psf = __expf(es);
    unsigned pvs = hp[(size_t)node * 16 + c];
    float accg = bf2f((unsigned short)pvs);
    float acca = bf2f((unsigned short)(pvs >> 16)) * psf;
    float lp = 0.f;
    int beg = rs[node], end = rs[node + 1];
    for (int j0 = beg; j0 < end; j0 += 16) {
        int cnt = min(16, end - j0);
        int sreg = 0;
        float pr = 0.f;
        if (c < cnt) {
            sreg = col[j0 + c];
            float e = s2s[sreg] + sd;
            e = (e >= 0.f) ? e : 0.2f * e;
            pr = __expf(e);
            lp += pr;
        }
        for (int e = 0; e < cnt; e += 4) {
            int si[4];
            float pi[4];
#pragma unroll
            for (int u = 0; u < 4; u++) {
                si[u] = __shfl(sreg, (e + u) & 15, 16);
                pi[u] = __shfl(pr, (e + u) & 15, 16);
            }
            unsigned hv[4];
#pragma unroll
            for (int u = 0; u < 4; u++) hv[u] = hp[(size_t)si[u] * 16 + c];
#pragma unroll
            for (int u = 0; u < 4; u++) {
                if (e + u < cnt) {
                    accg += bf2f((unsigned short)hv[u]);
                    acca += bf2f((unsigned short)(hv[u] >> 16)) * pi[u];
                }
            }
        }
    }
    for (int off = 8; off >= 1; off >>= 1) lp += __shfl_xor(lp, off, 16);
    float l = lp + psf;
    out[(size_t)node * 32 + c] = accg * di + bg2[c];
    out[(size_t)node * 32 + 16 + c] = acca / l + bga2[c];
}

// ---------------------------------------------------------------------------
// Launch
// ---------------------------------------------------------------------------
extern "C" void kernel_launch(void* const* d_in, const int* in_sizes, int n_in,
                              void* d_out, int out_size, void* d_ws, size_t ws_size,
                              hipStream_t stream) {
    const float* x      = (const float*)d_in[0];
    const int*   ei     = (const int*)d_in[1];
    const float* Wg1    = (const float*)d_in[2];
    const float* bg1    = (const float*)d_in[3];
    const float* Wg2    = (const float*)d_in[4];
    const float* bg2    = (const float*)d_in[5];
    const float* Wgat1  = (const float*)d_in[6];
    const float* a_src1 = (const float*)d_in[7];
    const float* a_dst1 = (const float*)d_in[8];
    const float* bgat1  = (const float*)d_in[9];
    const float* Wgat2  = (const float*)d_in[10];
    const float* a_src2 = (const float*)d_in[11];
    const float* a_dst2 = (const float*)d_in[12];
    const float* bgat2  = (const float*)d_in[13];
    float* out = (float*)d_out;

    const int* e_src = ei;
    const int* e_dst = ei + EE;

    char* wsb = (char*)d_ws;
    size_t o = 0;
    auto alloc = [&](size_t bytes) -> void* {
        void* p = wsb + o;
        o += (bytes + 255) & ~(size_t)255;
        return p;
    };
    // flags + partial FIRST (covered by one memset node)
    int* flags             = (int*)alloc(64);          // [0..15]
    int* partial           = (int*)alloc(256 * 4);
    float* dinv            = (float*)alloc(NN * 4);
    float* ssrc1           = (float*)alloc((size_t)NN * 16);
    float* sdst1           = (float*)alloc((size_t)NN * 16);
    unsigned short* h1b    = (unsigned short*)alloc((size_t)NN * HH * 2);
    unsigned short* xg1    = (unsigned short*)alloc((size_t)NN * HH * 2);
    unsigned short* hgb    = (unsigned short*)alloc((size_t)NN * 256 * 2);
    unsigned short* xgat1  = (unsigned short*)alloc((size_t)NN * 256 * 2);
    unsigned short* pairb  = (unsigned short*)alloc((size_t)NN * 16 * 4);
    float* s2src           = (float*)alloc(NN * 4);
    float* s2dst           = (float*)alloc(NN * 4);
    unsigned short* bhiC   = (unsigned short*)alloc((size_t)8 * NTT * 512 * 2);
    unsigned short* bhiG2  = (unsigned short*)alloc(64 * 16 * 2);
    unsigned short* bloG2  = (unsigned short*)alloc(64 * 16 * 2);
    unsigned short* bhiA2  = (unsigned short*)alloc(256 * 16 * 2);
    unsigned short* bloA2  = (unsigned short*)alloc(256 * 16 * 2);
    int* cnt               = (int*)alloc(NN * 4);
    int* rowstart          = (int*)alloc((NN + 1) * 4);
    int* cursor            = (int*)alloc(NN * 4);
    int* colarr            = (int*)alloc((size_t)EE * 4);

    const int TB = 256;
    // zero the flag/partial region (graph memset node)
    hipMemsetAsync(d_ws, 0, 2048, stream);

    // ONE-kernel CSR build + weight pack
    k_csr_build<<<CSRB, TB, 0, stream>>>(e_src, e_dst, Wg1, Wgat1, Wg2, Wgat2,
                                         bhiC, bhiG2, bloG2, bhiA2, bloA2,
                                         cnt, rowstart, cursor, dinv, colarr,
                                         flags, partial);

    const int GB = (NN + 63) / 64;    // 782
    const int G16 = (NN * 16) / 256;  // 3125

    mfma_gemm_fused<<<GB, TB, 0, stream>>>(x, bhiC, h1b, hgb, dinv,
                                           a_src1, a_dst1, ssrc1, sdst1, NN);

    both_agg<<<NN / 4, TB, 0, stream>>>(hgb, h1b, rowstart, colarr, ssrc1, sdst1,
                                        dinv, bgat1, bg1, xgat1, xg1);

    mfma_n16_both<<<2 * GB, TB, 0, stream>>>(xgat1, xg1, bhiA2, bloA2, bhiG2, bloG2,
                                             pairb, dinv, a_src2, a_dst2,
                                             s2src, s2dst, NN, GB);

    final_agg<<<G16, TB, 0, stream>>>((const unsigned*)pairb, rowstart, colarr, dinv,
                                      s2src, s2dst, bg2, bgat2, out);
}

// Round 15
// 364.202 us; speedup vs baseline: 1.4639x; 1.4639x over previous
//
#include <hip/hip_runtime.h>
#include <math.h>

#define NN     50000
#define FF     256
#define HH     64
#define NHEADS 4
#define EE     800000
#define OUTD   16

typedef __attribute__((ext_vector_type(8))) short short8;
typedef __attribute__((ext_vector_type(4))) float f32x4;

__device__ inline unsigned short f2bf(float f) {
    unsigned u = __builtin_bit_cast(unsigned, f);
    unsigned r = (u + 0x7fff + ((u >> 16) & 1)) >> 16;
    return (unsigned short)r;
}
__device__ inline float bf2f(unsigned short s) {
    unsigned u = ((unsigned)s) << 16;
    return __builtin_bit_cast(float, u);
}

// ---------------------------------------------------------------------------
// CSR build — separate kernels (round-14 lesson: device-scope spin-flag
// barriers cost ~250 us at 512 blocks; kernel boundaries are far cheaper).
// ---------------------------------------------------------------------------
__device__ inline void pack_one(const float* __restrict__ W,
                                unsigned short* __restrict__ bhi,
                                unsigned short* __restrict__ blo,
                                int t_, int NT, int NTOT, int TOFF, int SRC_NC) {
    int lane = t_ & 63;
    int tile = (t_ >> 6) % NT;
    int kb = (t_ >> 6) / NT;
    int q = lane >> 4, c = lane & 15;
    size_t off = ((size_t)(kb * NTOT + TOFF + tile) * 64 + lane) * 8;
#pragma unroll
    for (int j = 0; j < 8; j++) {
        float w = W[(size_t)(kb * 32 + q * 8 + j) * SRC_NC + tile * 16 + c];
        unsigned short h = f2bf(w);
        bhi[off + j] = h;
        if (blo) blo[off + j] = f2bf(w - bf2f(h));
    }
}

#define NTT 20
// zero cnt + pack all four weights, one launch (independent work).
__global__ __launch_bounds__(256) void k_prep(const float* __restrict__ Wg1,
                                              const float* __restrict__ Wgat1,
                                              const float* __restrict__ Wg2,
                                              const float* __restrict__ Wgat2,
                                              unsigned short* __restrict__ bhiC,
                                              unsigned short* __restrict__ bhiG2,
                                              unsigned short* __restrict__ bloG2,
                                              unsigned short* __restrict__ bhiA2,
                                              unsigned short* __restrict__ bloA2,
                                              int* __restrict__ cnt) {
    int t = blockIdx.x * 256 + threadIdx.x;
    if (t < NN) cnt[t] = 0;
    if (t < 2048)        pack_one(Wg1,   bhiC,  nullptr, t,         4,  NTT, 0, 64);
    else if (t < 10240)  pack_one(Wgat1, bhiC,  nullptr, t - 2048,  16, NTT, 4, 256);
    else if (t < 10368)  pack_one(Wg2,   bhiG2, bloG2,   t - 10240, 1,  1,   0, 16);
    else if (t < 10880)  pack_one(Wgat2, bhiA2, bloA2,   t - 10368, 1,  1,   0, 16);
}

__global__ void k_count(const int* __restrict__ dst, int* __restrict__ cnt, int e) {
    int i = blockIdx.x * blockDim.x + threadIdx.x;
    if (i < e) atomicAdd(&cnt[dst[i]], 1);
}

__global__ __launch_bounds__(256) void k_scan_a(const int* __restrict__ cnt,
                                                int* __restrict__ partial, int n) {
    int i = blockIdx.x * 256 + threadIdx.x;
    int v = (i < n) ? cnt[i] : 0;
#pragma unroll
    for (int off = 32; off >= 1; off >>= 1) v += __shfl_xor(v, off, 64);
    __shared__ int ws[4];
    int wave = threadIdx.x >> 6;
    if ((threadIdx.x & 63) == 0) ws[wave] = v;
    __syncthreads();
    if (threadIdx.x == 0) partial[blockIdx.x] = ws[0] + ws[1] + ws[2] + ws[3];
}

__global__ __launch_bounds__(256) void k_scan_b(const int* __restrict__ partial,
                                                int* __restrict__ blockoff,
                                                int* __restrict__ total_out, int nb) {
    __shared__ int arr[256];
    int tid = threadIdx.x;
    arr[tid] = (tid < nb) ? partial[tid] : 0;
    __syncthreads();
#pragma unroll
    for (int off = 1; off < 256; off <<= 1) {
        int v = arr[tid];
        int add = (tid >= off) ? arr[tid - off] : 0;
        __syncthreads();
        arr[tid] = v + add;
        __syncthreads();
    }
    if (tid < nb) blockoff[tid] = arr[tid] - partial[tid];
    if (tid == 0) *total_out = arr[255];
}

__global__ __launch_bounds__(256) void k_scan_c(const int* __restrict__ cnt,
                                                const int* __restrict__ blockoff,
                                                int* __restrict__ row_start,
                                                int* __restrict__ cursor,
                                                float* __restrict__ dinv, int n) {
    __shared__ int arr[256];
    int tid = threadIdx.x;
    int i = blockIdx.x * 256 + tid;
    int c = (i < n) ? cnt[i] : 0;
    arr[tid] = c;
    __syncthreads();
#pragma unroll
    for (int off = 1; off < 256; off <<= 1) {
        int v = arr[tid];
        int add = (tid >= off) ? arr[tid - off] : 0;
        __syncthreads();
        arr[tid] = v + add;
        __syncthreads();
    }
    if (i < n) {
        int excl = arr[tid] - c + blockoff[blockIdx.x];
        row_start[i] = excl;
        cursor[i] = excl;
        dinv[i] = rsqrtf((float)(c + 1));
    }
}

__global__ void k_fill(const int* __restrict__ src, const int* __restrict__ dst,
                       int* __restrict__ cursor, int* __restrict__ col, int e) {
    int i = blockIdx.x * blockDim.x + threadIdx.x;
    if (i < e) {
        int d = dst[i];
        int pos = atomicAdd(&cursor[d], 1);
        col[pos] = src[i];
    }
}

// ---------------------------------------------------------------------------
// FUSED big GEMM: one pass over x -> h1 (4 tiles, dinv-scaled) + hgat
// (16 tiles) + fused s1 scores. A split hi/lo (2 MFMAs/tile), B hi only.
// Barrier-free direct L2 reads of B (round-13). No async DMA (round-11).
// ---------------------------------------------------------------------------
__global__ __launch_bounds__(256) void mfma_gemm_fused(const float* __restrict__ A,
                                                       const unsigned short* __restrict__ Bhi,
                                                       unsigned short* __restrict__ Ch1,
                                                       unsigned short* __restrict__ Chg,
                                                       const float* __restrict__ dinv,
                                                       const float* __restrict__ a_s,
                                                       const float* __restrict__ a_d,
                                                       float* __restrict__ ssrc,
                                                       float* __restrict__ sdst,
                                                       int M) {
    const int K = 256;
    int tid = threadIdx.x;
    int w = tid >> 6, lane = tid & 63, q = lane >> 4, c = lane & 15;
    int row_base = blockIdx.x * 64 + w * 16;
    int ar = min(row_base + c, M - 1);
    const float* ap = A + (size_t)ar * K + q * 8;
    const short8* bp = (const short8*)Bhi + lane;

    f32x4 acc[NTT];
#pragma unroll
    for (int t = 0; t < NTT; t++) acc[t] = (f32x4){0.f, 0.f, 0.f, 0.f};

    for (int kb = 0; kb < 8; kb++) {
        float av[8];
        *(float4*)(av)     = *(const float4*)(ap + kb * 32);
        *(float4*)(av + 4) = *(const float4*)(ap + kb * 32 + 4);
        short8 ahi, alo;
#pragma unroll
        for (int j = 0; j < 8; j++) {
            unsigned short h = f2bf(av[j]);
            ahi[j] = (short)h;
            alo[j] = (short)f2bf(av[j] - bf2f(h));
        }
#pragma unroll
        for (int t = 0; t < NTT; t++) {
            short8 bhi = bp[(size_t)(kb * NTT + t) * 64];
            acc[t] = __builtin_amdgcn_mfma_f32_16x16x32_bf16(ahi, bhi, acc[t], 0, 0, 0);
            acc[t] = __builtin_amdgcn_mfma_f32_16x16x32_bf16(alo, bhi, acc[t], 0, 0, 0);
        }
    }

    // s1 scores over the 16 GAT tiles (tiles 4..19; head = (t-4)>>2)
#pragma unroll
    for (int i = 0; i < 4; i++) {
        int r = row_base + q * 4 + i;
        float ss[4] = {0.f, 0.f, 0.f, 0.f};
        float sd[4] = {0.f, 0.f, 0.f, 0.f};
#pragma unroll
        for (int t = 0; t < 16; t++) {
            float v = acc[t + 4][i];
            ss[t >> 2] += v * a_s[t * 16 + c];
            sd[t >> 2] += v * a_d[t * 16 + c];
        }
#pragma unroll
        for (int h = 0; h < 4; h++) {
#pragma unroll
            for (int off = 1; off <= 8; off <<= 1) {
                ss[h] += __shfl_xor(ss[h], off, 16);
                sd[h] += __shfl_xor(sd[h], off, 16);
            }
        }
        if (c == i && r < M) {
            *(float4*)(ssrc + (size_t)r * 4) = make_float4(ss[0], ss[1], ss[2], ss[3]);
            *(float4*)(sdst + (size_t)r * 4) = make_float4(sd[0], sd[1], sd[2], sd[3]);
        }
    }

#pragma unroll
    for (int i = 0; i < 4; i++) {
        int r = row_base + q * 4 + i;
        if (r < M) {
            float sc = dinv[r];
#pragma unroll
            for (int t = 0; t < 4; t++)
                Ch1[(size_t)r * 64 + t * 16 + c] = f2bf(acc[t][i] * sc);
#pragma unroll
            for (int t = 0; t < 16; t++)
                Chg[(size_t)r * 256 + t * 16 + c] = f2bf(acc[t + 4][i]);
        }
    }
}

// ---------------------------------------------------------------------------
// N=16 MFMA GEMM body; both small GEMMs in one launch (block-range split).
// ---------------------------------------------------------------------------
template <int KB, bool SCALE, bool SC2, int OFS>
__device__ inline void n16_body(int bx, int tid,
                                const unsigned short* __restrict__ A,
                                const unsigned short* __restrict__ Bhi,
                                const unsigned short* __restrict__ Blo,
                                unsigned short* __restrict__ Cbf,
                                const float* __restrict__ rowscale,
                                const float* __restrict__ a_s2,
                                const float* __restrict__ a_d2,
                                float* __restrict__ s2s,
                                float* __restrict__ s2d, int M) {
    const int K = KB * 32;
    int w = tid >> 6, lane = tid & 63, q = lane >> 4, c = lane & 15;
    int row_base = bx * 64 + w * 16;
    int ar = min(row_base + c, M - 1);
    const unsigned short* ap = A + (size_t)ar * K + q * 8;
    f32x4 acc = (f32x4){0.f, 0.f, 0.f, 0.f};
#pragma unroll
    for (int kb = 0; kb < KB; kb++) {
        short8 av = *(const short8*)(ap + kb * 32);
        size_t bo = ((size_t)kb * 64 + lane) * 8;
        short8 bh = *(const short8*)(Bhi + bo);
        short8 bl = *(const short8*)(Blo + bo);
        acc = __builtin_amdgcn_mfma_f32_16x16x32_bf16(av, bh, acc, 0, 0, 0);
        acc = __builtin_amdgcn_mfma_f32_16x16x32_bf16(av, bl, acc, 0, 0, 0);
    }
    if (SC2) {
#pragma unroll
        for (int i = 0; i < 4; i++) {
            float ps = acc[i] * a_s2[c];
            float pd = acc[i] * a_d2[c];
#pragma unroll
            for (int off = 1; off <= 8; off <<= 1) {
                ps += __shfl_xor(ps, off, 16);
                pd += __shfl_xor(pd, off, 16);
            }
            int r = row_base + q * 4 + i;
            if (c == i && r < M) {
                s2s[r] = ps;
                s2d[r] = pd;
            }
        }
    }
#pragma unroll
    for (int i = 0; i < 4; i++) {
        int r = row_base + q * 4 + i;
        if (r < M) {
            float sc = SCALE ? rowscale[r] : 1.0f;
            Cbf[((size_t)r * 16 + c) * 2 + OFS] = f2bf(acc[i] * sc);
        }
    }
}

__global__ __launch_bounds__(256) void mfma_n16_both(const unsigned short* __restrict__ Ag,
                                                     const unsigned short* __restrict__ Ac,
                                                     const unsigned short* __restrict__ bhiA2,
                                                     const unsigned short* __restrict__ bloA2,
                                                     const unsigned short* __restrict__ bhiG2,
                                                     const unsigned short* __restrict__ bloG2,
                                                     unsigned short* __restrict__ pairb,
                                                     const float* __restrict__ dinv,
                                                     const float* __restrict__ a_s2,
                                                     const float* __restrict__ a_d2,
                                                     float* __restrict__ s2s,
                                                     float* __restrict__ s2d,
                                                     int M, int GB) {
    int bx = blockIdx.x;
    if (bx < GB)
        n16_body<8, false, true, 1>(bx, threadIdx.x, Ag, bhiA2, bloA2, pairb,
                                    nullptr, a_s2, a_d2, s2s, s2d, M);
    else
        n16_body<2, true, false, 0>(bx - GB, threadIdx.x, Ac, bhiG2, bloG2, pairb,
                                    dinv, nullptr, nullptr, nullptr, nullptr, M);
}

// ---------------------------------------------------------------------------
// FUSED layer-1 aggregation: GAT1 (LDS-staged p/src, unroll-8 gather) +
// GCN1 riding the same sl[]. Fabric-floor bound (~3.6 TB/s FETCH-side).
// ---------------------------------------------------------------------------
__global__ __launch_bounds__(256) void both_agg(const unsigned short* __restrict__ hg,
                                                const unsigned short* __restrict__ h1,
                                                const int* __restrict__ rs,
                                                const int* __restrict__ col,
                                                const float* __restrict__ ssrc,
                                                const float* __restrict__ sdst,
                                                const float* __restrict__ dinv,
                                                const float* __restrict__ bgat,
                                                const float* __restrict__ bgcn,
                                                unsigned short* __restrict__ outg,
                                                unsigned short* __restrict__ outc) {
    __shared__ int s_lds[4][64];
    __shared__ float p_lds[4][64 * 4];
    int tid = threadIdx.x;
    int w = tid >> 6, lane = tid & 63;
    int wid = blockIdx.x * 4 + w;       // grid exact: 12500*4 = NN
    int hh = lane >> 4;
    int cidx = (lane & 15) * 4;
    int* sl = s_lds[w];
    float* pl = p_lds[w];

    float di = dinv[wid];
    float4 sd4 = *(const float4*)(sdst + (size_t)wid * 4);
    float sdv[4] = {sd4.x, sd4.y, sd4.z, sd4.w};
    float4 sf4 = *(const float4*)(ssrc + (size_t)wid * 4);
    float sfv[4] = {sf4.x, sf4.y, sf4.z, sf4.w};
    float psf[4];
#pragma unroll
    for (int h = 0; h < 4; h++) {
        float e = sfv[h] + sdv[h];
        e = (e >= 0.f) ? e : 0.2f * e;
        psf[h] = __expf(e);
    }
    float pse = (hh & 2) ? ((hh & 1) ? psf[3] : psf[2]) : ((hh & 1) ? psf[1] : psf[0]);
    const unsigned short* hbase = hg + lane * 4;
    ushort4 hvs = *(const ushort4*)(hbase + (size_t)wid * 256);
    float4 acc;
    acc.x = bf2f(hvs.x) * pse; acc.y = bf2f(hvs.y) * pse;
    acc.z = bf2f(hvs.z) * pse; acc.w = bf2f(hvs.w) * pse;
    float4 accc = make_float4(0.f, 0.f, 0.f, 0.f);

    float lsum[4] = {0.f, 0.f, 0.f, 0.f};
    int beg = rs[wid], end = rs[wid + 1];
    for (int j0 = beg; j0 < end; j0 += 64) {
        int cnt = min(64, end - j0);
        if (lane < cnt) {
            int sreg = col[j0 + lane];
            float4 sv = *(const float4*)(ssrc + (size_t)sreg * 4);
            float svv[4] = {sv.x, sv.y, sv.z, sv.w};
            float pv[4];
#pragma unroll
            for (int h = 0; h < 4; h++) {
                float e = svv[h] + sdv[h];
                e = (e >= 0.f) ? e : 0.2f * e;
                pv[h] = __expf(e);
                lsum[h] += pv[h];
            }
            sl[lane] = sreg;
            *(float4*)&pl[lane * 4] = make_float4(pv[0], pv[1], pv[2], pv[3]);
        }
        // same-wave LDS write->read: DS pipe in-order per wave, no barrier
        int e = 0;
        for (; e + 8 <= cnt; e += 8) {
            int sv0[8]; float pv0[8]; ushort4 hv[8];
#pragma unroll
            for (int u = 0; u < 8; u++) {
                sv0[u] = sl[e + u];
                pv0[u] = pl[(e + u) * 4 + hh];
            }
#pragma unroll
            for (int u = 0; u < 8; u++)
                hv[u] = *(const ushort4*)(hbase + (size_t)sv0[u] * 256);
#pragma unroll
            for (int u = 0; u < 8; u++) {
                acc.x += bf2f(hv[u].x) * pv0[u];
                acc.y += bf2f(hv[u].y) * pv0[u];
                acc.z += bf2f(hv[u].z) * pv0[u];
                acc.w += bf2f(hv[u].w) * pv0[u];
            }
        }
        for (; e < cnt; e++) {
            int s = sl[e];
            float p = pl[e * 4 + hh];
            ushort4 hv = *(const ushort4*)(hbase + (size_t)s * 256);
            acc.x += bf2f(hv.x) * p; acc.y += bf2f(hv.y) * p;
            acc.z += bf2f(hv.z) * p; acc.w += bf2f(hv.w) * p;
        }
        // GCN gather: group hh handles edges {hh, hh+4, ...}, 2 in flight
        int e2 = hh;
        for (; e2 + 4 < cnt; e2 += 8) {
            int sa = sl[e2], sb = sl[e2 + 4];
            ushort4 va = *(const ushort4*)(h1 + (size_t)sa * HH + cidx);
            ushort4 vb = *(const ushort4*)(h1 + (size_t)sb * HH + cidx);
            accc.x += bf2f(va.x) + bf2f(vb.x);
            accc.y += bf2f(va.y) + bf2f(vb.y);
            accc.z += bf2f(va.z) + bf2f(vb.z);
            accc.w += bf2f(va.w) + bf2f(vb.w);
        }
        if (e2 < cnt) {
            int sa = sl[e2];
            ushort4 va = *(const ushort4*)(h1 + (size_t)sa * HH + cidx);
            accc.x += bf2f(va.x); accc.y += bf2f(va.y);
            accc.z += bf2f(va.z); accc.w += bf2f(va.w);
        }
    }
    // GAT epilogue
#pragma unroll
    for (int h = 0; h < 4; h++) {
        float v = lsum[h];
        for (int off = 32; off >= 1; off >>= 1) v += __shfl_xor(v, off, 64);
        lsum[h] = v + psf[h];
    }
    float lt = (hh & 2) ? ((hh & 1) ? lsum[3] : lsum[2]) : ((hh & 1) ? lsum[1] : lsum[0]);
    float li = 1.0f / lt;
    float4 bv = *(const float4*)(bgat + lane * 4);
    ushort4 o;
    o.x = f2bf(fmaxf(acc.x * li + bv.x, 0.f));
    o.y = f2bf(fmaxf(acc.y * li + bv.y, 0.f));
    o.z = f2bf(fmaxf(acc.z * li + bv.z, 0.f));
    o.w = f2bf(fmaxf(acc.w * li + bv.w, 0.f));
    *(ushort4*)(outg + (size_t)wid * 256 + lane * 4) = o;
    // GCN epilogue
#pragma unroll
    for (int off = 16; off <= 32; off <<= 1) {
        accc.x += __shfl_xor(accc.x, off, 64);
        accc.y += __shfl_xor(accc.y, off, 64);
        accc.z += __shfl_xor(accc.z, off, 64);
        accc.w += __shfl_xor(accc.w, off, 64);
    }
    if (hh == 0) {
        ushort4 sv = *(const ushort4*)(h1 + (size_t)wid * HH + cidx);
        float4 bc = *(const float4*)(bgcn + cidx);
        ushort4 oc;
        oc.x = f2bf(fmaxf((accc.x + bf2f(sv.x)) * di + bc.x, 0.f));
        oc.y = f2bf(fmaxf((accc.y + bf2f(sv.y)) * di + bc.y, 0.f));
        oc.z = f2bf(fmaxf((accc.z + bf2f(sv.z)) * di + bc.z, 0.f));
        oc.w = f2bf(fmaxf((accc.w + bf2f(sv.w)) * di + bc.w, 0.f));
        *(ushort4*)(outc + (size_t)wid * HH + cidx) = oc;
    }
}

// ---------------------------------------------------------------------------
// Final aggregation: fused GCN2 + GAT2 over the interleaved pair buffer.
// ---------------------------------------------------------------------------
__global__ __launch_bounds__(256) void final_agg(const unsigned* __restrict__ hp,
                                                 const int* __restrict__ rs,
                                                 const int* __restrict__ col,
                                                 const float* __restrict__ dinv,
                                                 const float* __restrict__ s2s,
                                                 const float* __restrict__ s2d,
                                                 const float* __restrict__ bg2,
                                                 const float* __restrict__ bga2,
                                                 float* __restrict__ out) {
    int t = blockIdx.x * 256 + threadIdx.x;
    int node = t >> 4;
    int c = t & 15;
    float di = dinv[node];
    float sd = s2d[node];
    float es = s2s[node] + sd;
    es = (es >= 0.f) ? es : 0.2f * es;
    float psf = __expf(es);
    unsigned pvs = hp[(size_t)node * 16 + c];
    float accg = bf2f((unsigned short)pvs);
    float acca = bf2f((unsigned short)(pvs >> 16)) * psf;
    float lp = 0.f;
    int beg = rs[node], end = rs[node + 1];
    for (int j0 = beg; j0 < end; j0 += 16) {
        int cnt = min(16, end - j0);
        int sreg = 0;
        float pr = 0.f;
        if (c < cnt) {
            sreg = col[j0 + c];
            float e = s2s[sreg] + sd;
            e = (e >= 0.f) ? e : 0.2f * e;
            pr = __expf(e);
            lp += pr;
        }
        for (int e = 0; e < cnt; e += 4) {
            int si[4];
            float pi[4];
#pragma unroll
            for (int u = 0; u < 4; u++) {
                si[u] = __shfl(sreg, (e + u) & 15, 16);
                pi[u] = __shfl(pr, (e + u) & 15, 16);
            }
            unsigned hv[4];
#pragma unroll
            for (int u = 0; u < 4; u++) hv[u] = hp[(size_t)si[u] * 16 + c];
#pragma unroll
            for (int u = 0; u < 4; u++) {
                if (e + u < cnt) {
                    accg += bf2f((unsigned short)hv[u]);
                    acca += bf2f((unsigned short)(hv[u] >> 16)) * pi[u];
                }
            }
        }
    }
    for (int off = 8; off >= 1; off >>= 1) lp += __shfl_xor(lp, off, 16);
    float l = lp + psf;
    out[(size_t)node * 32 + c] = accg * di + bg2[c];
    out[(size_t)node * 32 + 16 + c] = acca / l + bga2[c];
}

// ---------------------------------------------------------------------------
// Launch
// ---------------------------------------------------------------------------
extern "C" void kernel_launch(void* const* d_in, const int* in_sizes, int n_in,
                              void* d_out, int out_size, void* d_ws, size_t ws_size,
                              hipStream_t stream) {
    const float* x      = (const float*)d_in[0];
    const int*   ei     = (const int*)d_in[1];
    const float* Wg1    = (const float*)d_in[2];
    const float* bg1    = (const float*)d_in[3];
    const float* Wg2    = (const float*)d_in[4];
    const float* bg2    = (const float*)d_in[5];
    const float* Wgat1  = (const float*)d_in[6];
    const float* a_src1 = (const float*)d_in[7];
    const float* a_dst1 = (const float*)d_in[8];
    const float* bgat1  = (const float*)d_in[9];
    const float* Wgat2  = (const float*)d_in[10];
    const float* a_src2 = (const float*)d_in[11];
    const float* a_dst2 = (const float*)d_in[12];
    const float* bgat2  = (const float*)d_in[13];
    float* out = (float*)d_out;

    const int* e_src = ei;
    const int* e_dst = ei + EE;

    char* wsb = (char*)d_ws;
    size_t o = 0;
    auto alloc = [&](size_t bytes) -> void* {
        void* p = wsb + o;
        o += (bytes + 255) & ~(size_t)255;
        return p;
    };
    float* dinv            = (float*)alloc(NN * 4);
    float* ssrc1           = (float*)alloc((size_t)NN * 16);
    float* sdst1           = (float*)alloc((size_t)NN * 16);
    unsigned short* h1b    = (unsigned short*)alloc((size_t)NN * HH * 2);
    unsigned short* xg1    = (unsigned short*)alloc((size_t)NN * HH * 2);
    unsigned short* hgb    = (unsigned short*)alloc((size_t)NN * 256 * 2);
    unsigned short* xgat1  = (unsigned short*)alloc((size_t)NN * 256 * 2);
    unsigned short* pairb  = (unsigned short*)alloc((size_t)NN * 16 * 4);
    float* s2src           = (float*)alloc(NN * 4);
    float* s2dst           = (float*)alloc(NN * 4);
    unsigned short* bhiC   = (unsigned short*)alloc((size_t)8 * NTT * 512 * 2);
    unsigned short* bhiG2  = (unsigned short*)alloc(64 * 16 * 2);
    unsigned short* bloG2  = (unsigned short*)alloc(64 * 16 * 2);
    unsigned short* bhiA2  = (unsigned short*)alloc(256 * 16 * 2);
    unsigned short* bloA2  = (unsigned short*)alloc(256 * 16 * 2);
    int* cnt               = (int*)alloc(NN * 4);
    int* rowstart          = (int*)alloc((NN + 1) * 4);
    int* cursor            = (int*)alloc(NN * 4);
    int* colarr            = (int*)alloc((size_t)EE * 4);
    int* partial           = (int*)alloc(256 * 4);
    int* blockoff          = (int*)alloc(256 * 4);

    const int TB = 256;
    const int NB = (NN + 255) / 256;
    // CSR build + weight packing (zero merged into pack)
    k_prep<<<NB, TB, 0, stream>>>(Wg1, Wgat1, Wg2, Wgat2,
                                  bhiC, bhiG2, bloG2, bhiA2, bloA2, cnt);
    k_count<<<(EE + TB - 1) / TB, TB, 0, stream>>>(e_dst, cnt, EE);
    k_scan_a<<<NB, TB, 0, stream>>>(cnt, partial, NN);
    k_scan_b<<<1, TB, 0, stream>>>(partial, blockoff, rowstart + NN, NB);
    k_scan_c<<<NB, TB, 0, stream>>>(cnt, blockoff, rowstart, cursor, dinv, NN);
    k_fill<<<(EE + TB - 1) / TB, TB, 0, stream>>>(e_src, e_dst, cursor, colarr, EE);

    const int GB = (NN + 63) / 64;    // 782
    const int G16 = (NN * 16) / 256;  // 3125

    mfma_gemm_fused<<<GB, TB, 0, stream>>>(x, bhiC, h1b, hgb, dinv,
                                           a_src1, a_dst1, ssrc1, sdst1, NN);

    both_agg<<<NN / 4, TB, 0, stream>>>(hgb, h1b, rowstart, colarr, ssrc1, sdst1,
                                        dinv, bgat1, bg1, xgat1, xg1);

    mfma_n16_both<<<2 * GB, TB, 0, stream>>>(xgat1, xg1, bhiA2, bloA2, bhiG2, bloG2,
                                             pairb, dinv, a_src2, a_dst2,
                                             s2src, s2dst, NN, GB);

    final_agg<<<G16, TB, 0, stream>>>((const unsigned*)pairb, rowstart, colarr, dinv,
                                      s2src, s2dst, bg2, bgat2, out);
}

// Round 16
// 349.817 us; speedup vs baseline: 1.5241x; 1.0411x over previous
//
#include <hip/hip_runtime.h>
#include <math.h>

#define NN     50000
#define FF     256
#define HH     64
#define NHEADS 4
#define EE     800000
#define OUTD   16

typedef __attribute__((ext_vector_type(8))) short short8;
typedef __attribute__((ext_vector_type(4))) float f32x4;

__device__ inline unsigned short f2bf(float f) {
    unsigned u = __builtin_bit_cast(unsigned, f);
    unsigned r = (u + 0x7fff + ((u >> 16) & 1)) >> 16;
    return (unsigned short)r;
}
__device__ inline float bf2f(unsigned short s) {
    unsigned u = ((unsigned)s) << 16;
    return __builtin_bit_cast(float, u);
}

// ---------------------------------------------------------------------------
// CSR build — separate kernels (round-14 lesson: device-scope spin-flag
// barriers cost ~250 us; kernel boundaries are far cheaper).
// ---------------------------------------------------------------------------
__device__ inline void pack_one(const float* __restrict__ W,
                                unsigned short* __restrict__ bhi,
                                unsigned short* __restrict__ blo,
                                int t_, int NT, int NTOT, int TOFF, int SRC_NC) {
    int lane = t_ & 63;
    int tile = (t_ >> 6) % NT;
    int kb = (t_ >> 6) / NT;
    int q = lane >> 4, c = lane & 15;
    size_t off = ((size_t)(kb * NTOT + TOFF + tile) * 64 + lane) * 8;
#pragma unroll
    for (int j = 0; j < 8; j++) {
        float w = W[(size_t)(kb * 32 + q * 8 + j) * SRC_NC + tile * 16 + c];
        unsigned short h = f2bf(w);
        bhi[off + j] = h;
        if (blo) blo[off + j] = f2bf(w - bf2f(h));
    }
}

#define NTT 20
// zero cnt + pack all four weights, one launch (independent work).
__global__ __launch_bounds__(256) void k_prep(const float* __restrict__ Wg1,
                                              const float* __restrict__ Wgat1,
                                              const float* __restrict__ Wg2,
                                              const float* __restrict__ Wgat2,
                                              unsigned short* __restrict__ bhiC,
                                              unsigned short* __restrict__ bhiG2,
                                              unsigned short* __restrict__ bloG2,
                                              unsigned short* __restrict__ bhiA2,
                                              unsigned short* __restrict__ bloA2,
                                              int* __restrict__ cnt) {
    int t = blockIdx.x * 256 + threadIdx.x;
    if (t < NN) cnt[t] = 0;
    if (t < 2048)        pack_one(Wg1,   bhiC,  nullptr, t,         4,  NTT, 0, 64);
    else if (t < 10240)  pack_one(Wgat1, bhiC,  nullptr, t - 2048,  16, NTT, 4, 256);
    else if (t < 10368)  pack_one(Wg2,   bhiG2, bloG2,   t - 10240, 1,  1,   0, 16);
    else if (t < 10880)  pack_one(Wgat2, bhiA2, bloA2,   t - 10368, 1,  1,   0, 16);
}

__global__ void k_count(const int* __restrict__ dst, int* __restrict__ cnt, int e) {
    int i = blockIdx.x * blockDim.x + threadIdx.x;
    if (i < e) atomicAdd(&cnt[dst[i]], 1);
}

__global__ __launch_bounds__(256) void k_scan_a(const int* __restrict__ cnt,
                                                int* __restrict__ partial, int n) {
    int i = blockIdx.x * 256 + threadIdx.x;
    int v = (i < n) ? cnt[i] : 0;
#pragma unroll
    for (int off = 32; off >= 1; off >>= 1) v += __shfl_xor(v, off, 64);
    __shared__ int ws[4];
    int wave = threadIdx.x >> 6;
    if ((threadIdx.x & 63) == 0) ws[wave] = v;
    __syncthreads();
    if (threadIdx.x == 0) partial[blockIdx.x] = ws[0] + ws[1] + ws[2] + ws[3];
}

__global__ __launch_bounds__(256) void k_scan_b(const int* __restrict__ partial,
                                                int* __restrict__ blockoff,
                                                int* __restrict__ total_out, int nb) {
    __shared__ int arr[256];
    int tid = threadIdx.x;
    arr[tid] = (tid < nb) ? partial[tid] : 0;
    __syncthreads();
#pragma unroll
    for (int off = 1; off < 256; off <<= 1) {
        int v = arr[tid];
        int add = (tid >= off) ? arr[tid - off] : 0;
        __syncthreads();
        arr[tid] = v + add;
        __syncthreads();
    }
    if (tid < nb) blockoff[tid] = arr[tid] - partial[tid];
    if (tid == 0) *total_out = arr[255];
}

__global__ __launch_bounds__(256) void k_scan_c(const int* __restrict__ cnt,
                                                const int* __restrict__ blockoff,
                                                int* __restrict__ row_start,
                                                int* __restrict__ cursor,
                                                float* __restrict__ dinv, int n) {
    __shared__ int arr[256];
    int tid = threadIdx.x;
    int i = blockIdx.x * 256 + tid;
    int c = (i < n) ? cnt[i] : 0;
    arr[tid] = c;
    __syncthreads();
#pragma unroll
    for (int off = 1; off < 256; off <<= 1) {
        int v = arr[tid];
        int add = (tid >= off) ? arr[tid - off] : 0;
        __syncthreads();
        arr[tid] = v + add;
        __syncthreads();
    }
    if (i < n) {
        int excl = arr[tid] - c + blockoff[blockIdx.x];
        row_start[i] = excl;
        cursor[i] = excl;
        dinv[i] = rsqrtf((float)(c + 1));
    }
}

__global__ void k_fill(const int* __restrict__ src, const int* __restrict__ dst,
                       int* __restrict__ cursor, int* __restrict__ col, int e) {
    int i = blockIdx.x * blockDim.x + threadIdx.x;
    if (i < e) {
        int d = dst[i];
        int pos = atomicAdd(&cursor[d], 1);
        col[pos] = src[i];
    }
}

// ---------------------------------------------------------------------------
// FUSED big GEMM: one pass over x -> h1 (4 tiles, dinv-scaled) + hgat
// (16 tiles) + fused s1 scores. A split hi/lo (2 MFMAs/tile), B hi only.
// Barrier-free direct L2 reads of B (round-13). No async DMA (round-11).
// ---------------------------------------------------------------------------
__global__ __launch_bounds__(256) void mfma_gemm_fused(const float* __restrict__ A,
                                                       const unsigned short* __restrict__ Bhi,
                                                       unsigned short* __restrict__ Ch1,
                                                       unsigned short* __restrict__ Chg,
                                                       const float* __restrict__ dinv,
                                                       const float* __restrict__ a_s,
                                                       const float* __restrict__ a_d,
                                                       float* __restrict__ ssrc,
                                                       float* __restrict__ sdst,
                                                       int M) {
    const int K = 256;
    int tid = threadIdx.x;
    int w = tid >> 6, lane = tid & 63, q = lane >> 4, c = lane & 15;
    int row_base = blockIdx.x * 64 + w * 16;
    int ar = min(row_base + c, M - 1);
    const float* ap = A + (size_t)ar * K + q * 8;
    const short8* bp = (const short8*)Bhi + lane;

    f32x4 acc[NTT];
#pragma unroll
    for (int t = 0; t < NTT; t++) acc[t] = (f32x4){0.f, 0.f, 0.f, 0.f};

    for (int kb = 0; kb < 8; kb++) {
        float av[8];
        *(float4*)(av)     = *(const float4*)(ap + kb * 32);
        *(float4*)(av + 4) = *(const float4*)(ap + kb * 32 + 4);
        short8 ahi, alo;
#pragma unroll
        for (int j = 0; j < 8; j++) {
            unsigned short h = f2bf(av[j]);
            ahi[j] = (short)h;
            alo[j] = (short)f2bf(av[j] - bf2f(h));
        }
#pragma unroll
        for (int t = 0; t < NTT; t++) {
            short8 bhi = bp[(size_t)(kb * NTT + t) * 64];
            acc[t] = __builtin_amdgcn_mfma_f32_16x16x32_bf16(ahi, bhi, acc[t], 0, 0, 0);
            acc[t] = __builtin_amdgcn_mfma_f32_16x16x32_bf16(alo, bhi, acc[t], 0, 0, 0);
        }
    }

    // s1 scores over the 16 GAT tiles (tiles 4..19; head = (t-4)>>2)
#pragma unroll
    for (int i = 0; i < 4; i++) {
        int r = row_base + q * 4 + i;
        float ss[4] = {0.f, 0.f, 0.f, 0.f};
        float sd[4] = {0.f, 0.f, 0.f, 0.f};
#pragma unroll
        for (int t = 0; t < 16; t++) {
            float v = acc[t + 4][i];
            ss[t >> 2] += v * a_s[t * 16 + c];
            sd[t >> 2] += v * a_d[t * 16 + c];
        }
#pragma unroll
        for (int h = 0; h < 4; h++) {
#pragma unroll
            for (int off = 1; off <= 8; off <<= 1) {
                ss[h] += __shfl_xor(ss[h], off, 16);
                sd[h] += __shfl_xor(sd[h], off, 16);
            }
        }
        if (c == i && r < M) {
            *(float4*)(ssrc + (size_t)r * 4) = make_float4(ss[0], ss[1], ss[2], ss[3]);
            *(float4*)(sdst + (size_t)r * 4) = make_float4(sd[0], sd[1], sd[2], sd[3]);
        }
    }

#pragma unroll
    for (int i = 0; i < 4; i++) {
        int r = row_base + q * 4 + i;
        if (r < M) {
            float sc = dinv[r];
#pragma unroll
            for (int t = 0; t < 4; t++)
                Ch1[(size_t)r * 64 + t * 16 + c] = f2bf(acc[t][i] * sc);
#pragma unroll
            for (int t = 0; t < 16; t++)
                Chg[(size_t)r * 256 + t * 16 + c] = f2bf(acc[t + 4][i]);
        }
    }
}

// ---------------------------------------------------------------------------
// N=16 MFMA GEMM body; both small GEMMs in one launch (block-range split).
// ---------------------------------------------------------------------------
template <int KB, bool SCALE, bool SC2, int OFS>
__device__ inline void n16_body(int bx, int tid,
                                const unsigned short* __restrict__ A,
                                const unsigned short* __restrict__ Bhi,
                                const unsigned short* __restrict__ Blo,
                                unsigned short* __restrict__ Cbf,
                                const float* __restrict__ rowscale,
                                const float* __restrict__ a_s2,
                                const float* __restrict__ a_d2,
                                float* __restrict__ s2s,
                                float* __restrict__ s2d, int M) {
    const int K = KB * 32;
    int w = tid >> 6, lane = tid & 63, q = lane >> 4, c = lane & 15;
    int row_base = bx * 64 + w * 16;
    int ar = min(row_base + c, M - 1);
    const unsigned short* ap = A + (size_t)ar * K + q * 8;
    f32x4 acc = (f32x4){0.f, 0.f, 0.f, 0.f};
#pragma unroll
    for (int kb = 0; kb < KB; kb++) {
        short8 av = *(const short8*)(ap + kb * 32);
        size_t bo = ((size_t)kb * 64 + lane) * 8;
        short8 bh = *(const short8*)(Bhi + bo);
        short8 bl = *(const short8*)(Blo + bo);
        acc = __builtin_amdgcn_mfma_f32_16x16x32_bf16(av, bh, acc, 0, 0, 0);
        acc = __builtin_amdgcn_mfma_f32_16x16x32_bf16(av, bl, acc, 0, 0, 0);
    }
    if (SC2) {
#pragma unroll
        for (int i = 0; i < 4; i++) {
            float ps = acc[i] * a_s2[c];
            float pd = acc[i] * a_d2[c];
#pragma unroll
            for (int off = 1; off <= 8; off <<= 1) {
                ps += __shfl_xor(ps, off, 16);
                pd += __shfl_xor(pd, off, 16);
            }
            int r = row_base + q * 4 + i;
            if (c == i && r < M) {
                s2s[r] = ps;
                s2d[r] = pd;
            }
        }
    }
#pragma unroll
    for (int i = 0; i < 4; i++) {
        int r = row_base + q * 4 + i;
        if (r < M) {
            float sc = SCALE ? rowscale[r] : 1.0f;
            Cbf[((size_t)r * 16 + c) * 2 + OFS] = f2bf(acc[i] * sc);
        }
    }
}

__global__ __launch_bounds__(256) void mfma_n16_both(const unsigned short* __restrict__ Ag,
                                                     const unsigned short* __restrict__ Ac,
                                                     const unsigned short* __restrict__ bhiA2,
                                                     const unsigned short* __restrict__ bloA2,
                                                     const unsigned short* __restrict__ bhiG2,
                                                     const unsigned short* __restrict__ bloG2,
                                                     unsigned short* __restrict__ pairb,
                                                     const float* __restrict__ dinv,
                                                     const float* __restrict__ a_s2,
                                                     const float* __restrict__ a_d2,
                                                     float* __restrict__ s2s,
                                                     float* __restrict__ s2d,
                                                     int M, int GB) {
    int bx = blockIdx.x;
    if (bx < GB)
        n16_body<8, false, true, 1>(bx, threadIdx.x, Ag, bhiA2, bloA2, pairb,
                                    nullptr, a_s2, a_d2, s2s, s2d, M);
    else
        n16_body<2, true, false, 0>(bx - GB, threadIdx.x, Ac, bhiG2, bloG2, pairb,
                                    dinv, nullptr, nullptr, nullptr, nullptr, M);
}

// ---------------------------------------------------------------------------
// FUSED layer-1 aggregation: GAT1 (LDS-staged p/src, UNROLL-4 gather —
// round-15 lesson: unroll-8 cost a VGPR step (36->44) and occupancy
// (64->45%), regressing 85->95 us) + GCN1 riding the same sl[].
// Fabric-floor bound (~3.6 TB/s FETCH-side).
// ---------------------------------------------------------------------------
__global__ __launch_bounds__(256) void both_agg(const unsigned short* __restrict__ hg,
                                                const unsigned short* __restrict__ h1,
                                                const int* __restrict__ rs,
                                                const int* __restrict__ col,
                                                const float* __restrict__ ssrc,
                                                const float* __restrict__ sdst,
                                                const float* __restrict__ dinv,
                                                const float* __restrict__ bgat,
                                                const float* __restrict__ bgcn,
                                                unsigned short* __restrict__ outg,
                                                unsigned short* __restrict__ outc) {
    __shared__ int s_lds[4][64];
    __shared__ float p_lds[4][64 * 4];
    int tid = threadIdx.x;
    int w = tid >> 6, lane = tid & 63;
    int wid = blockIdx.x * 4 + w;       // grid exact: 12500*4 = NN
    int hh = lane >> 4;
    int cidx = (lane & 15) * 4;
    int* sl = s_lds[w];
    float* pl = p_lds[w];

    float di = dinv[wid];
    float4 sd4 = *(const float4*)(sdst + (size_t)wid * 4);
    float sdv[4] = {sd4.x, sd4.y, sd4.z, sd4.w};
    float4 sf4 = *(const float4*)(ssrc + (size_t)wid * 4);
    float sfv[4] = {sf4.x, sf4.y, sf4.z, sf4.w};
    float psf[4];
#pragma unroll
    for (int h = 0; h < 4; h++) {
        float e = sfv[h] + sdv[h];
        e = (e >= 0.f) ? e : 0.2f * e;
        psf[h] = __expf(e);
    }
    float pse = (hh & 2) ? ((hh & 1) ? psf[3] : psf[2]) : ((hh & 1) ? psf[1] : psf[0]);
    const unsigned short* hbase = hg + lane * 4;
    ushort4 hvs = *(const ushort4*)(hbase + (size_t)wid * 256);
    float4 acc;
    acc.x = bf2f(hvs.x) * pse; acc.y = bf2f(hvs.y) * pse;
    acc.z = bf2f(hvs.z) * pse; acc.w = bf2f(hvs.w) * pse;
    float4 accc = make_float4(0.f, 0.f, 0.f, 0.f);

    float lsum[4] = {0.f, 0.f, 0.f, 0.f};
    int beg = rs[wid], end = rs[wid + 1];
    for (int j0 = beg; j0 < end; j0 += 64) {
        int cnt = min(64, end - j0);
        if (lane < cnt) {
            int sreg = col[j0 + lane];
            float4 sv = *(const float4*)(ssrc + (size_t)sreg * 4);
            float svv[4] = {sv.x, sv.y, sv.z, sv.w};
            float pv[4];
#pragma unroll
            for (int h = 0; h < 4; h++) {
                float e = svv[h] + sdv[h];
                e = (e >= 0.f) ? e : 0.2f * e;
                pv[h] = __expf(e);
                lsum[h] += pv[h];
            }
            sl[lane] = sreg;
            *(float4*)&pl[lane * 4] = make_float4(pv[0], pv[1], pv[2], pv[3]);
        }
        // same-wave LDS write->read: DS pipe in-order per wave, no barrier
        int e = 0;
        for (; e + 4 <= cnt; e += 4) {
            int s0 = sl[e], s1 = sl[e + 1], s2 = sl[e + 2], s3 = sl[e + 3];
            float p0 = pl[e * 4 + hh], p1 = pl[(e + 1) * 4 + hh];
            float p2 = pl[(e + 2) * 4 + hh], p3 = pl[(e + 3) * 4 + hh];
            ushort4 h0 = *(const ushort4*)(hbase + (size_t)s0 * 256);
            ushort4 h1v = *(const ushort4*)(hbase + (size_t)s1 * 256);
            ushort4 h2 = *(const ushort4*)(hbase + (size_t)s2 * 256);
            ushort4 h3 = *(const ushort4*)(hbase + (size_t)s3 * 256);
            acc.x += bf2f(h0.x) * p0; acc.y += bf2f(h0.y) * p0;
            acc.z += bf2f(h0.z) * p0; acc.w += bf2f(h0.w) * p0;
            acc.x += bf2f(h1v.x) * p1; acc.y += bf2f(h1v.y) * p1;
            acc.z += bf2f(h1v.z) * p1; acc.w += bf2f(h1v.w) * p1;
            acc.x += bf2f(h2.x) * p2; acc.y += bf2f(h2.y) * p2;
            acc.z += bf2f(h2.z) * p2; acc.w += bf2f(h2.w) * p2;
            acc.x += bf2f(h3.x) * p3; acc.y += bf2f(h3.y) * p3;
            acc.z += bf2f(h3.z) * p3; acc.w += bf2f(h3.w) * p3;
        }
        for (; e < cnt; e++) {
            int s = sl[e];
            float p = pl[e * 4 + hh];
            ushort4 hv = *(const ushort4*)(hbase + (size_t)s * 256);
            acc.x += bf2f(hv.x) * p; acc.y += bf2f(hv.y) * p;
            acc.z += bf2f(hv.z) * p; acc.w += bf2f(hv.w) * p;
        }
        // GCN gather: group hh handles edges {hh, hh+4, ...}, 2 in flight
        int e2 = hh;
        for (; e2 + 4 < cnt; e2 += 8) {
            int sa = sl[e2], sb = sl[e2 + 4];
            ushort4 va = *(const ushort4*)(h1 + (size_t)sa * HH + cidx);
            ushort4 vb = *(const ushort4*)(h1 + (size_t)sb * HH + cidx);
            accc.x += bf2f(va.x) + bf2f(vb.x);
            accc.y += bf2f(va.y) + bf2f(vb.y);
            accc.z += bf2f(va.z) + bf2f(vb.z);
            accc.w += bf2f(va.w) + bf2f(vb.w);
        }
        if (e2 < cnt) {
            int sa = sl[e2];
            ushort4 va = *(const ushort4*)(h1 + (size_t)sa * HH + cidx);
            accc.x += bf2f(va.x); accc.y += bf2f(va.y);
            accc.z += bf2f(va.z); accc.w += bf2f(va.w);
        }
    }
    // GAT epilogue
#pragma unroll
    for (int h = 0; h < 4; h++) {
        float v = lsum[h];
        for (int off = 32; off >= 1; off >>= 1) v += __shfl_xor(v, off, 64);
        lsum[h] = v + psf[h];
    }
    float lt = (hh & 2) ? ((hh & 1) ? lsum[3] : lsum[2]) : ((hh & 1) ? lsum[1] : lsum[0]);
    float li = 1.0f / lt;
    float4 bv = *(const float4*)(bgat + lane * 4);
    ushort4 o;
    o.x = f2bf(fmaxf(acc.x * li + bv.x, 0.f));
    o.y = f2bf(fmaxf(acc.y * li + bv.y, 0.f));
    o.z = f2bf(fmaxf(acc.z * li + bv.z, 0.f));
    o.w = f2bf(fmaxf(acc.w * li + bv.w, 0.f));
    *(ushort4*)(outg + (size_t)wid * 256 + lane * 4) = o;
    // GCN epilogue
#pragma unroll
    for (int off = 16; off <= 32; off <<= 1) {
        accc.x += __shfl_xor(accc.x, off, 64);
        accc.y += __shfl_xor(accc.y, off, 64);
        accc.z += __shfl_xor(accc.z, off, 64);
        accc.w += __shfl_xor(accc.w, off, 64);
    }
    if (hh == 0) {
        ushort4 sv = *(const ushort4*)(h1 + (size_t)wid * HH + cidx);
        float4 bc = *(const float4*)(bgcn + cidx);
        ushort4 oc;
        oc.x = f2bf(fmaxf((accc.x + bf2f(sv.x)) * di + bc.x, 0.f));
        oc.y = f2bf(fmaxf((accc.y + bf2f(sv.y)) * di + bc.y, 0.f));
        oc.z = f2bf(fmaxf((accc.z + bf2f(sv.z)) * di + bc.z, 0.f));
        oc.w = f2bf(fmaxf((accc.w + bf2f(sv.w)) * di + bc.w, 0.f));
        *(ushort4*)(outc + (size_t)wid * HH + cidx) = oc;
    }
}

// ---------------------------------------------------------------------------
// Final aggregation: fused GCN2 + GAT2 over the interleaved pair buffer.
// ---------------------------------------------------------------------------
__global__ __launch_bounds__(256) void final_agg(const unsigned* __restrict__ hp,
                                                 const int* __restrict__ rs,
                                                 const int* __restrict__ col,
                                                 const float* __restrict__ dinv,
                                                 const float* __restrict__ s2s,
                                                 const float* __restrict__ s2d,
                                                 const float* __restrict__ bg2,
                                                 const float* __restrict__ bga2,
                                                 float* __restrict__ out) {
    int t = blockIdx.x * 256 + threadIdx.x;
    int node = t >> 4;
    int c = t & 15;
    float di = dinv[node];
    float sd = s2d[node];
    float es = s2s[node] + sd;
    es = (es >= 0.f) ? es : 0.2f * es;
    float psf = __expf(es);
    unsigned pvs = hp[(size_t)node * 16 + c];
    float accg = bf2f((unsigned short)pvs);
    float acca = bf2f((unsigned short)(pvs >> 16)) * psf;
    float lp = 0.f;
    int beg = rs[node], end = rs[node + 1];
    for (int j0 = beg; j0 < end; j0 += 16) {
        int cnt = min(16, end - j0);
        int sreg = 0;
        float pr = 0.f;
        if (c < cnt) {
            sreg = col[j0 + c];
            float e = s2s[sreg] + sd;
            e = (e >= 0.f) ? e : 0.2f * e;
            pr = __expf(e);
            lp += pr;
        }
        for (int e = 0; e < cnt; e += 4) {
            int si[4];
            float pi[4];
#pragma unroll
            for (int u = 0; u < 4; u++) {
                si[u] = __shfl(sreg, (e + u) & 15, 16);
                pi[u] = __shfl(pr, (e + u) & 15, 16);
            }
            unsigned hv[4];
#pragma unroll
            for (int u = 0; u < 4; u++) hv[u] = hp[(size_t)si[u] * 16 + c];
#pragma unroll
            for (int u = 0; u < 4; u++) {
                if (e + u < cnt) {
                    accg += bf2f((unsigned short)hv[u]);
                    acca += bf2f((unsigned short)(hv[u] >> 16)) * pi[u];
                }
            }
        }
    }
    for (int off = 8; off >= 1; off >>= 1) lp += __shfl_xor(lp, off, 16);
    float l = lp + psf;
    out[(size_t)node * 32 + c] = accg * di + bg2[c];
    out[(size_t)node * 32 + 16 + c] = acca / l + bga2[c];
}

// ---------------------------------------------------------------------------
// Launch
// ---------------------------------------------------------------------------
extern "C" void kernel_launch(void* const* d_in, const int* in_sizes, int n_in,
                              void* d_out, int out_size, void* d_ws, size_t ws_size,
                              hipStream_t stream) {
    const float* x      = (const float*)d_in[0];
    const int*   ei     = (const int*)d_in[1];
    const float* Wg1    = (const float*)d_in[2];
    const float* bg1    = (const float*)d_in[3];
    const float* Wg2    = (const float*)d_in[4];
    const float* bg2    = (const float*)d_in[5];
    const float* Wgat1  = (const float*)d_in[6];
    const float* a_src1 = (const float*)d_in[7];
    const float* a_dst1 = (const float*)d_in[8];
    const float* bgat1  = (const float*)d_in[9];
    const float* Wgat2  = (const float*)d_in[10];
    const float* a_src2 = (const float*)d_in[11];
    const float* a_dst2 = (const float*)d_in[12];
    const float* bgat2  = (const float*)d_in[13];
    float* out = (float*)d_out;

    const int* e_src = ei;
    const int* e_dst = ei + EE;

    char* wsb = (char*)d_ws;
    size_t o = 0;
    auto alloc = [&](size_t bytes) -> void* {
        void* p = wsb + o;
        o += (bytes + 255) & ~(size_t)255;
        return p;
    };
    float* dinv            = (float*)alloc(NN * 4);
    float* ssrc1           = (float*)alloc((size_t)NN * 16);
    float* sdst1           = (float*)alloc((size_t)NN * 16);
    unsigned short* h1b    = (unsigned short*)alloc((size_t)NN * HH * 2);
    unsigned short* xg1    = (unsigned short*)alloc((size_t)NN * HH * 2);
    unsigned short* hgb    = (unsigned short*)alloc((size_t)NN * 256 * 2);
    unsigned short* xgat1  = (unsigned short*)alloc((size_t)NN * 256 * 2);
    unsigned short* pairb  = (unsigned short*)alloc((size_t)NN * 16 * 4);
    float* s2src           = (float*)alloc(NN * 4);
    float* s2dst           = (float*)alloc(NN * 4);
    unsigned short* bhiC   = (unsigned short*)alloc((size_t)8 * NTT * 512 * 2);
    unsigned short* bhiG2  = (unsigned short*)alloc(64 * 16 * 2);
    unsigned short* bloG2  = (unsigned short*)alloc(64 * 16 * 2);
    unsigned short* bhiA2  = (unsigned short*)alloc(256 * 16 * 2);
    unsigned short* bloA2  = (unsigned short*)alloc(256 * 16 * 2);
    int* cnt               = (int*)alloc(NN * 4);
    int* rowstart          = (int*)alloc((NN + 1) * 4);
    int* cursor            = (int*)alloc(NN * 4);
    int* colarr            = (int*)alloc((size_t)EE * 4);
    int* partial           = (int*)alloc(256 * 4);
    int* blockoff          = (int*)alloc(256 * 4);

    const int TB = 256;
    const int NB = (NN + 255) / 256;
    // CSR build + weight packing (zero merged into pack)
    k_prep<<<NB, TB, 0, stream>>>(Wg1, Wgat1, Wg2, Wgat2,
                                  bhiC, bhiG2, bloG2, bhiA2, bloA2, cnt);
    k_count<<<(EE + TB - 1) / TB, TB, 0, stream>>>(e_dst, cnt, EE);
    k_scan_a<<<NB, TB, 0, stream>>>(cnt, partial, NN);
    k_scan_b<<<1, TB, 0, stream>>>(partial, blockoff, rowstart + NN, NB);
    k_scan_c<<<NB, TB, 0, stream>>>(cnt, blockoff, rowstart, cursor, dinv, NN);
    k_fill<<<(EE + TB - 1) / TB, TB, 0, stream>>>(e_src, e_dst, cursor, colarr, EE);

    const int GB = (NN + 63) / 64;    // 782
    const int G16 = (NN * 16) / 256;  // 3125

    mfma_gemm_fused<<<GB, TB, 0, stream>>>(x, bhiC, h1b, hgb, dinv,
                                           a_src1, a_dst1, ssrc1, sdst1, NN);

    both_agg<<<NN / 4, TB, 0, stream>>>(hgb, h1b, rowstart, colarr, ssrc1, sdst1,
                                        dinv, bgat1, bg1, xgat1, xg1);

    mfma_n16_both<<<2 * GB, TB, 0, stream>>>(xgat1, xg1, bhiA2, bloA2, bhiG2, bloG2,
                                             pairb, dinv, a_src2, a_dst2,
                                             s2src, s2dst, NN, GB);

    final_agg<<<G16, TB, 0, stream>>>((const unsigned*)pairb, rowstart, colarr, dinv,
                                      s2src, s2dst, bg2, bgat2, out);
}